// Round 7
// baseline (1459.441 us; speedup 1.0000x reference)
//
#include <hip/hip_runtime.h>
#include <hip/hip_cooperative_groups.h>
#include <cstdint>

namespace cg = cooperative_groups;

#define N_NODES 100000
#define NBKT 2048      // dst buckets (1<<11)
#define KNODE 49       // nodes per bucket: ceil(100000/2048)
#define GB 512         // grid blocks (co-resident: 2/CU needed, <=128 VGPR)
#define TB 256         // threads per block
#define NWAVE (GB * TB / 64)   // 2048 waves
#define CAP 2048       // LDS staging per bucket (mean 1562, large margin)

// LDS union across phases (max ~16.5 KB)
union SMem {
    int ih[NBKT];                                          // hist / place cursors
    int sc[256];                                           // bucket-total scan
    struct { int sE[CAP]; int cnt[64]; int pfx[64]; int cur[64]; } fin;
    float wt[8 * 512];                                     // gemm1 W1^T
    struct { float w[128]; float b[16]; } g2;              // W2/b2
    struct { float v[32]; float c2[2]; } g3;               // folded head
};

struct Params {
    const float* x; const int* src; const int* dst; const int2* smp;
    const float* W1; const float* b1; const float* W2; const float* b2;
    const float* W3; const float* b3; const float* Wfc; const float* bfc;
    float* out;
    int E; int S;
    int* hist; int* offs; int* tmp; int* btot; int* bbase;
    int* row_start; float* dinv; int* csr;
    float* xw1; float* h1; float* h2; float* pi; float* pj;
};

__global__ __launch_bounds__(TB) void mega(Params p) {
    cg::grid_group grid = cg::this_grid();
    __shared__ SMem sm;
    const int tid = threadIdx.x;
    const int bid = blockIdx.x;
    const int wid = (bid * TB + tid) >> 6;
    const int lane = tid & 63;

    // ---------- P1: per-block LDS histogram over dst buckets ----------
    for (int i = tid; i < NBKT; i += TB) sm.ih[i] = 0;
    __syncthreads();
    const int chunk = (p.E + GB - 1) / GB;
    const int lo = bid * chunk, hi = min(lo + chunk, p.E);
    for (int i = lo + tid; i < hi; i += TB)
        atomicAdd(&sm.ih[p.dst[i] / KNODE], 1);
    __syncthreads();
    for (int i = tid; i < NBKT; i += TB) p.hist[(size_t)bid * NBKT + i] = sm.ih[i];
    grid.sync();

    // ---------- P2: column prefix over blocks (wave per bucket, XCD-grouped order) ----------
    {
        int bkt = wid;                       // 2048 waves == NBKT
        int vals[8], loc[8];
        int s = 0;
#pragma unroll
        for (int j = 0; j < 8; ++j) {
            int rr = lane * 8 + j;
            int r = ((rr & 63) << 3) | (rr >> 6);   // same-XCD blocks adjacent segments
            vals[j] = p.hist[(size_t)r * NBKT + bkt];
            loc[j] = s; s += vals[j];
        }
        int inc = s;
#pragma unroll
        for (int o = 1; o < 64; o <<= 1) { int u = __shfl_up(inc, o); if (lane >= o) inc += u; }
        int excl = inc - s;
#pragma unroll
        for (int j = 0; j < 8; ++j) {
            int rr = lane * 8 + j;
            int r = ((rr & 63) << 3) | (rr >> 6);
            p.offs[(size_t)r * NBKT + bkt] = excl + loc[j];
        }
        if (lane == 63) p.btot[bkt] = excl + s;
    }
    grid.sync();

    // ---------- P3: exclusive scan of 2048 bucket totals (block 0) ----------
    if (bid == 0) {
        int loc[8], sum = 0;
#pragma unroll
        for (int j = 0; j < 8; ++j) { loc[j] = p.btot[tid * 8 + j]; sum += loc[j]; }
        sm.sc[tid] = sum;
        __syncthreads();
        for (int o = 1; o < 256; o <<= 1) {
            int v = (tid >= o) ? sm.sc[tid - o] : 0;
            __syncthreads(); sm.sc[tid] += v; __syncthreads();
        }
        int base = sm.sc[tid] - sum;
#pragma unroll
        for (int j = 0; j < 8; ++j) { p.bbase[tid * 8 + j] = base; base += loc[j]; }
        if (tid == 255) p.bbase[NBKT] = base;
    }
    grid.sync();

    // ---------- P4: place packed edges at deterministic offsets (LDS cursors) ----------
    {
        const int* orow = p.offs + (size_t)bid * NBKT;
        for (int i = tid; i < NBKT; i += TB) sm.ih[i] = p.bbase[i] + orow[i];
        __syncthreads();
        for (int i = lo + tid; i < hi; i += TB) {
            int d = p.dst[i], s = p.src[i];
            int b = d / KNODE;
            int pos = atomicAdd(&sm.ih[b], 1);   // LDS atomic
            p.tmp[pos] = (s << 6) | (d - b * KNODE);
        }
    }
    grid.sync();

    // ---------- P5: finalize — count + prefix -> row_start/dinv, place csr (src only) ----------
    for (int bi = 0; bi < NBKT / GB; ++bi) {
        int b = bid * (NBKT / GB) + bi;
        __syncthreads();
        if (tid < 64) sm.fin.cnt[tid] = 0;
        __syncthreads();
        int n0 = p.bbase[b], n1 = p.bbase[b + 1];
        int m = n1 - n0;
        for (int i = tid; i < m; i += TB) {
            int e = p.tmp[n0 + i];
            if (i < CAP) sm.fin.sE[i] = e;
            atomicAdd(&sm.fin.cnt[e & 63], 1);
        }
        __syncthreads();
        if (tid == 0) {
            int run = n0;
            for (int j = 0; j < KNODE; ++j) { sm.fin.pfx[j] = run; run += sm.fin.cnt[j]; }
        }
        __syncthreads();
        if (tid < KNODE) {
            int node = b * KNODE + tid;
            if (node < N_NODES) {
                p.row_start[node] = sm.fin.pfx[tid];
                p.dinv[node] = rsqrtf((float)sm.fin.cnt[tid] + 1.0f);
            }
            sm.fin.cur[tid] = sm.fin.pfx[tid];
        }
        if (b == 0 && tid == 0) p.row_start[N_NODES] = p.bbase[NBKT];
        __syncthreads();
        for (int i = tid; i < m; i += TB) {
            int e = (i < CAP) ? sm.fin.sE[i] : p.tmp[n0 + i];
            int pos = atomicAdd(&sm.fin.cur[e & 63], 1);   // LDS atomic
            p.csr[pos] = e >> 6;
        }
    }
    grid.sync();

    // ---------- P6: xw1' = (x @ W1) * dinv, wave-cooperative (8 rows/wave) ----------
    __syncthreads();
    for (int i = tid; i < 4096; i += TB) { int k = i >> 3, c = i & 7; sm.wt[c * 512 + k] = p.W1[i]; }
    __syncthreads();
    {
        int r_sub = lane >> 3, j = lane & 7;
        for (int rg = wid; rg < N_NODES / 8; rg += NWAVE) {
            int row = rg * 8 + r_sub;                      // N_NODES % 8 == 0
            const float* xr = p.x + (size_t)row * 512;
            float acc[8];
#pragma unroll
            for (int c = 0; c < 8; ++c) acc[c] = 0.f;
#pragma unroll 4
            for (int it = 0; it < 16; ++it) {
                int kb = it * 32 + j * 4;
                float4 v = *(const float4*)(xr + kb);
#pragma unroll
                for (int c = 0; c < 8; ++c) {
                    const float* wt = &sm.wt[c * 512 + kb];
                    acc[c] += v.x * wt[0] + v.y * wt[1] + v.z * wt[2] + v.w * wt[3];
                }
            }
#pragma unroll
            for (int o = 1; o < 8; o <<= 1)
#pragma unroll
                for (int c = 0; c < 8; ++c) acc[c] += __shfl_xor(acc[c], o);
            float outv = acc[0];
#pragma unroll
            for (int c = 1; c < 8; ++c) if (j == c) outv = acc[c];
            p.xw1[(size_t)row * 8 + j] = outv * p.dinv[row];
        }
    }
    grid.sync();

    // ---------- P7: h1' = relu(dinv*agg8(xw1') + b1) * dinv ----------
    {
        int e8 = lane >> 3, c = lane & 7;
        for (int node = wid; node < N_NODES; node += NWAVE) {
            int k0 = p.row_start[node], k1 = p.row_start[node + 1];
            float acc = 0.f;
            for (int k = k0 + e8; k < k1; k += 8)
                acc += p.xw1[(size_t)p.csr[k] * 8 + c];
            if (e8 == 0) acc += p.xw1[(size_t)node * 8 + c];
#pragma unroll
            for (int o = 8; o < 64; o <<= 1) acc += __shfl_xor(acc, o);
            if (lane < 8) {
                float di = p.dinv[node];
                p.h1[(size_t)node * 8 + c] = fmaxf(acc * di + p.b1[c], 0.f) * di;
            }
        }
    }
    grid.sync();

    // ---------- P8: h2' = relu((dinv*agg8(h1'))@W2 + b2) * dinv ----------
    __syncthreads();
    if (tid < 128) sm.g2.w[tid] = p.W2[tid];
    if (tid < 16) sm.g2.b[tid] = p.b2[tid];
    __syncthreads();
    {
        int e8 = lane >> 3, c = lane & 7;
        for (int node = wid; node < N_NODES; node += NWAVE) {
            int k0 = p.row_start[node], k1 = p.row_start[node + 1];
            float acc = 0.f;
            for (int k = k0 + e8; k < k1; k += 8)
                acc += p.h1[(size_t)p.csr[k] * 8 + c];
            if (e8 == 0) acc += p.h1[(size_t)node * 8 + c];
#pragma unroll
            for (int o = 8; o < 64; o <<= 1) acc += __shfl_xor(acc, o);
            float di = p.dinv[node];
            acc *= di;
            float s2[8];
#pragma unroll
            for (int k = 0; k < 8; ++k) s2[k] = __shfl(acc, k);
            if (lane < 16) {
                float a = sm.g2.b[lane];
#pragma unroll
                for (int k = 0; k < 8; ++k) a += s2[k] * sm.g2.w[k * 16 + lane];
                p.h2[(size_t)node * 16 + lane] = fmaxf(a, 0.f) * di;
            }
        }
    }
    grid.sync();

    // ---------- P9: folded head per block, then pi/pj from dinv*agg16(h2') ----------
    __syncthreads();
    if (tid < 32) {
        int j = tid & 15;
        const float* wf = p.Wfc + (tid < 16 ? 0 : 32);
        float a = 0.f;
        for (int k = 0; k < 32; ++k) a += p.W3[j * 32 + k] * wf[k];
        sm.g3.v[tid] = a;
    } else if (tid < 34) {
        const float* wf = p.Wfc + (tid == 32 ? 0 : 32);
        float a = 0.f;
        for (int k = 0; k < 32; ++k) a += p.b3[k] * wf[k];
        sm.g3.c2[tid - 32] = a;
    }
    __syncthreads();
    {
        int e4 = lane >> 4, c = lane & 15;
        for (int node = wid; node < N_NODES; node += NWAVE) {
            int k0 = p.row_start[node], k1 = p.row_start[node + 1];
            float acc = 0.f;
            for (int k = k0 + e4; k < k1; k += 4)
                acc += p.h2[(size_t)p.csr[k] * 16 + c];
            if (e4 == 0) acc += p.h2[(size_t)node * 16 + c];
#pragma unroll
            for (int o = 16; o < 64; o <<= 1) acc += __shfl_xor(acc, o);
            float t = acc * sm.g3.v[c];
            float u = acc * sm.g3.v[16 + c];
#pragma unroll
            for (int o = 1; o < 16; o <<= 1) {
                t += __shfl_xor(t, o);
                u += __shfl_xor(u, o);
            }
            if (lane == 0) {
                float di = p.dinv[node];
                p.pi[node] = t * di + sm.g3.c2[0];
                p.pj[node] = u * di + sm.g3.c2[1];
            }
        }
    }
    grid.sync();

    // ---------- P10: per-sample sigmoid ----------
    {
        float bfc0 = p.bfc[0];
        for (int i = bid * TB + tid; i < p.S; i += GB * TB) {
            int2 s = p.smp[i];
            float z = p.pi[s.x] + p.pj[s.y] + bfc0;
            p.out[i] = 1.0f / (1.0f + __expf(-z));
        }
    }
}

// ---------------- launch ----------------

extern "C" void kernel_launch(void* const* d_in, const int* in_sizes, int n_in,
                              void* d_out, int out_size, void* d_ws, size_t ws_size,
                              hipStream_t stream) {
    const float* x   = (const float*)d_in[0];
    const int*   ei  = (const int*)d_in[1];
    const int*   smp = (const int*)d_in[2];

    const int E = in_sizes[1] / 2;
    const int S = in_sizes[2] / 2;
    const int N = N_NODES;

    char* w = (char*)d_ws;
    size_t off = 0;
    auto alloc = [&](size_t bytes) {
        char* p = w + off;
        off += (bytes + 255) & ~(size_t)255;
        return p;
    };
    int*   row_start = (int*)alloc((N + 1) * 4);
    float* dinv      = (float*)alloc(N * 4);
    int*   csr       = (int*)alloc((size_t)E * 4);
    int*   btot      = (int*)alloc(NBKT * 4);
    int*   bbase     = (int*)alloc((NBKT + 1) * 4);

    // layer buffers; tmp/hist/offs (partition scratch, ~21MB) overlay this
    // region — all dead before P6 runs.
    size_t off_layers = off;
    float* xw1       = (float*)alloc((size_t)N * 8 * 4);
    float* h1        = (float*)alloc((size_t)N * 8 * 4);
    float* h2        = (float*)alloc((size_t)N * 16 * 4);
    float* pi        = (float*)alloc(N * 4);
    float* pj        = (float*)alloc(N * 4);

    size_t tmp_off  = off_layers;
    size_t hist_off = tmp_off + (((size_t)E * 4 + 255) & ~(size_t)255);
    size_t offs_off = hist_off + (((size_t)GB * NBKT * 4 + 255) & ~(size_t)255);
    int* tmp  = (int*)(w + tmp_off);
    int* hist = (int*)(w + hist_off);
    int* offs = (int*)(w + offs_off);
    size_t scratch_end = offs_off + (size_t)GB * NBKT * 4;
    if (scratch_end > off) off = (scratch_end + 255) & ~(size_t)255;

    Params prm;
    prm.x = x; prm.src = ei; prm.dst = ei + E; prm.smp = (const int2*)smp;
    prm.W1 = (const float*)d_in[3];  prm.b1 = (const float*)d_in[4];
    prm.W2 = (const float*)d_in[5];  prm.b2 = (const float*)d_in[6];
    prm.W3 = (const float*)d_in[7];  prm.b3 = (const float*)d_in[8];
    prm.Wfc = (const float*)d_in[9]; prm.bfc = (const float*)d_in[10];
    prm.out = (float*)d_out;
    prm.E = E; prm.S = S;
    prm.hist = hist; prm.offs = offs; prm.tmp = tmp; prm.btot = btot; prm.bbase = bbase;
    prm.row_start = row_start; prm.dinv = dinv; prm.csr = csr;
    prm.xw1 = xw1; prm.h1 = h1; prm.h2 = h2; prm.pi = pi; prm.pj = pj;

    void* args[] = { &prm };
    hipLaunchCooperativeKernel((const void*)mega, dim3(GB), dim3(TB), args, 0, stream);
}